// Round 6
// baseline (625.497 us; speedup 1.0000x reference)
//
#include <hip/hip_runtime.h>
#include <math.h>

#define N_TOK 4096
#define DM 1024
#define DFF 4096
#define DN 128
#define NH 8
#define HD 16
#define KSEL 32
#define KCAND 48
#define KMAX 64

typedef __attribute__((ext_vector_type(4))) float floatx4;
typedef __attribute__((ext_vector_type(8))) short short8;
typedef __attribute__((ext_vector_type(8))) unsigned short ushort8v;
typedef __attribute__((ext_vector_type(4))) unsigned short ushort4v;

__device__ __forceinline__ float gelu_f(float x) {
  return 0.5f * x * (1.0f + erff(x * 0.70710678118654752440f));
}
__device__ __forceinline__ float bf2f(unsigned short u) {
  union { unsigned int i; float f; } v; v.i = ((unsigned int)u) << 16; return v.f;
}
__device__ __forceinline__ unsigned short f2bf(float f) {
  unsigned int x = __float_as_uint(f);
  unsigned int r = (x + 0x7fffu + ((x >> 16) & 1u)) >> 16;
  return (unsigned short)r;
}

// ---------------- LayerNorm ----------------
__global__ __launch_bounds__(256) void ln_kernel(const float* __restrict__ x,
    const float* __restrict__ g, const float* __restrict__ b, float* __restrict__ xn) {
  int n = blockIdx.x, tid = threadIdx.x;
  const float* row = x + (size_t)n * DM;
  float s = 0.f, sq = 0.f;
  for (int i = tid; i < DM; i += 256) { float v = row[i]; s += v; sq += v * v; }
  for (int off = 32; off; off >>= 1) { s += __shfl_down(s, off); sq += __shfl_down(sq, off); }
  __shared__ float ss[4], ssq[4];
  __shared__ float s_mu, s_rs;
  int wid = tid >> 6;
  if ((tid & 63) == 0) { ss[wid] = s; ssq[wid] = sq; }
  __syncthreads();
  if (tid == 0) {
    float S = ss[0] + ss[1] + ss[2] + ss[3];
    float Q = ssq[0] + ssq[1] + ssq[2] + ssq[3];
    float mu = S * (1.f / DM);
    float var = Q * (1.f / DM) - mu * mu;
    s_mu = mu; s_rs = rsqrtf(var + 1e-5f);
  }
  __syncthreads();
  float mu = s_mu, rs = s_rs;
  float* o = xn + (size_t)n * DM;
  for (int i = tid; i < DM; i += 256) o[i] = (row[i] - mu) * rs * g[i] + b[i];
}

// ---------------- gemm1: h = gelu(xn @ rw1^T), fp32, + bf16 copy ----------------
// Tile 256(M) x 32(N), K-step 32. 256 threads; wave lanes = M -> B is
// wave-uniform (broadcast LDS reads), A is one contiguous b32/lane/kk.
// k-major LDS: As stride 257 (conflict-free col reads), Bs stride 36 (aligned b128).
#define G1_SA 257
#define G1_SB 36
__global__ __launch_bounds__(256) void gemm1_kernel(const float* __restrict__ A,
    const float* __restrict__ B, float* __restrict__ C, unsigned short* __restrict__ Cb) {
  __shared__ float As[32 * G1_SA];
  __shared__ float Bs[32 * G1_SB];
  const int K = DM, N = DM;
  int tid = threadIdx.x;
  int rr = tid >> 3;            // 0..31
  int cc = (tid & 7) * 4;       // 0,4,..,28
  const float* Ab = A + (size_t)blockIdx.y * 256 * K;
  const float* Bb = B + (size_t)blockIdx.x * 32 * K;

  float acc[32];
#pragma unroll
  for (int j = 0; j < 32; j++) acc[j] = 0.f;

  float4 av[8];
  float4 bv;
  // preload tile 0
#pragma unroll
  for (int i = 0; i < 8; i++)
    av[i] = *(const float4*)(Ab + (size_t)(i * 32 + rr) * K + cc);
  bv = *(const float4*)(Bb + (size_t)rr * K + cc);

  for (int k0 = 0; k0 < K; k0 += 32) {
    __syncthreads();
#pragma unroll
    for (int i = 0; i < 8; i++) {
      int m = i * 32 + rr;
#pragma unroll
      for (int j = 0; j < 4; j++) As[(cc + j) * G1_SA + m] = av[i][j];
    }
#pragma unroll
    for (int j = 0; j < 4; j++) Bs[(cc + j) * G1_SB + rr] = bv[j];
    __syncthreads();

    if (k0 + 32 < K) {
#pragma unroll
      for (int i = 0; i < 8; i++)
        av[i] = *(const float4*)(Ab + (size_t)(i * 32 + rr) * K + k0 + 32 + cc);
      bv = *(const float4*)(Bb + (size_t)rr * K + k0 + 32 + cc);
    }

#pragma unroll 8
    for (int kk = 0; kk < 32; kk++) {
      float va = As[kk * G1_SA + tid];
      float4 b0 = *(const float4*)&Bs[kk * G1_SB + 0];
      float4 b1 = *(const float4*)&Bs[kk * G1_SB + 4];
      float4 b2 = *(const float4*)&Bs[kk * G1_SB + 8];
      float4 b3 = *(const float4*)&Bs[kk * G1_SB + 12];
      float4 b4 = *(const float4*)&Bs[kk * G1_SB + 16];
      float4 b5 = *(const float4*)&Bs[kk * G1_SB + 20];
      float4 b6 = *(const float4*)&Bs[kk * G1_SB + 24];
      float4 b7 = *(const float4*)&Bs[kk * G1_SB + 28];
#pragma unroll
      for (int e = 0; e < 4; e++) {
        acc[0 + e]  = fmaf(va, b0[e], acc[0 + e]);
        acc[4 + e]  = fmaf(va, b1[e], acc[4 + e]);
        acc[8 + e]  = fmaf(va, b2[e], acc[8 + e]);
        acc[12 + e] = fmaf(va, b3[e], acc[12 + e]);
        acc[16 + e] = fmaf(va, b4[e], acc[16 + e]);
        acc[20 + e] = fmaf(va, b5[e], acc[20 + e]);
        acc[24 + e] = fmaf(va, b6[e], acc[24 + e]);
        acc[28 + e] = fmaf(va, b7[e], acc[28 + e]);
      }
    }
  }

  size_t m = (size_t)blockIdx.y * 256 + tid;
  size_t cbase = m * N + (size_t)blockIdx.x * 32;
#pragma unroll
  for (int q = 0; q < 8; q++) {
    float4 v;
#pragma unroll
    for (int e = 0; e < 4; e++) v[e] = gelu_f(acc[q * 4 + e]);
    *(float4*)(C + cbase + q * 4) = v;
    ushort4v o = {f2bf(v.x), f2bf(v.y), f2bf(v.z), f2bf(v.w)};
    *(ushort4v*)(Cb + cbase + q * 4) = o;
  }
}

// ---------------- generic fp32 -> bf16 convert ----------------
__global__ __launch_bounds__(256) void cvt_bf16(const float* __restrict__ in,
    unsigned short* __restrict__ out) {
  int i = (blockIdx.x * 256 + threadIdx.x) * 4;
  float4 v = *(const float4*)(in + i);
  ushort4v o = {f2bf(v.x), f2bf(v.y), f2bf(v.z), f2bf(v.w)};
  *(ushort4v*)(out + i) = o;
}

// ---------------- bf16 MFMA GEMM: scores_approx(bf16) = hb @ w2b^T ----------------
__global__ __launch_bounds__(256) void gemm_bf(const unsigned short* __restrict__ Ah,
    const unsigned short* __restrict__ Bh, unsigned short* __restrict__ C) {
  __shared__ short Asd[128 * 32];
  __shared__ short Bsd[128 * 32];
  const int K = 1024;
  int tid = threadIdx.x;
  int w = tid >> 6, l = tid & 63;
  size_t brow = (size_t)blockIdx.y * 128;
  size_t bcol = (size_t)blockIdx.x * 128;
  const short* Ab = (const short*)Ah + brow * K;
  const short* Bb = (const short*)Bh + bcol * K;

  int r0 = w * 32 + (l >> 2);
  int g0 = (l & 3) ^ ((r0 >> 1) & 3);
  const short* Ag0 = Ab + (size_t)r0 * K + g0 * 8;
  const short* Ag1 = Ab + (size_t)(r0 + 16) * K + g0 * 8;
  const short* Bg0 = Bb + (size_t)r0 * K + g0 * 8;
  const short* Bg1 = Bb + (size_t)(r0 + 16) * K + g0 * 8;
  short* ALds0 = &Asd[w * 1024];
  short* ALds1 = &Asd[w * 1024 + 512];
  short* BLds0 = &Bsd[w * 1024];
  short* BLds1 = &Bsd[w * 1024 + 512];

  const short8* aptr[4];
  const short8* bptr[4];
#pragma unroll
  for (int i = 0; i < 4; i++) {
    int m = (w >> 1) * 64 + i * 16 + (l & 15);
    int slot = m * 4 + ((l >> 4) ^ ((m >> 1) & 3));
    aptr[i] = (const short8*)&Asd[slot * 8];
    int n = (w & 1) * 64 + i * 16 + (l & 15);
    int slotb = n * 4 + ((l >> 4) ^ ((n >> 1) & 3));
    bptr[i] = (const short8*)&Bsd[slotb * 8];
  }

  floatx4 acc[4][4];
#pragma unroll
  for (int i = 0; i < 4; i++)
#pragma unroll
    for (int j = 0; j < 4; j++) acc[i][j] = (floatx4){0.f, 0.f, 0.f, 0.f};

  for (int k0 = 0; k0 < K; k0 += 32) {
    __syncthreads();
    __builtin_amdgcn_global_load_lds((const __attribute__((address_space(1))) unsigned int*)(Ag0 + k0),
                                     (__attribute__((address_space(3))) unsigned int*)ALds0, 16, 0, 0);
    __builtin_amdgcn_global_load_lds((const __attribute__((address_space(1))) unsigned int*)(Ag1 + k0),
                                     (__attribute__((address_space(3))) unsigned int*)ALds1, 16, 0, 0);
    __builtin_amdgcn_global_load_lds((const __attribute__((address_space(1))) unsigned int*)(Bg0 + k0),
                                     (__attribute__((address_space(3))) unsigned int*)BLds0, 16, 0, 0);
    __builtin_amdgcn_global_load_lds((const __attribute__((address_space(1))) unsigned int*)(Bg1 + k0),
                                     (__attribute__((address_space(3))) unsigned int*)BLds1, 16, 0, 0);
    __syncthreads();
    short8 a[4], b[4];
#pragma unroll
    for (int i = 0; i < 4; i++) a[i] = *aptr[i];
#pragma unroll
    for (int j = 0; j < 4; j++) b[j] = *bptr[j];
#pragma unroll
    for (int i = 0; i < 4; i++)
#pragma unroll
      for (int j = 0; j < 4; j++)
        acc[i][j] = __builtin_amdgcn_mfma_f32_16x16x32_bf16(a[i], b[j], acc[i][j], 0, 0, 0);
  }

#pragma unroll
  for (int i = 0; i < 4; i++) {
#pragma unroll
    for (int j = 0; j < 4; j++) {
#pragma unroll
      for (int r = 0; r < 4; r++) {
        size_t row = brow + (w >> 1) * 64 + i * 16 + (l >> 4) * 4 + r;
        size_t col = bcol + (w & 1) * 64 + j * 16 + (l & 15);
        C[row * DFF + col] = f2bf(acc[i][j][r]);
      }
    }
  }
}

// ---------------- top-candidates per row: wave-per-token radix select ----------------
__global__ __launch_bounds__(256) void topk2_kernel(const unsigned short* __restrict__ scores,
    int* __restrict__ cand, int* __restrict__ cnt) {
  int wv = threadIdx.x >> 6, l = threadIdx.x & 63;
  int n = blockIdx.x * 4 + wv;
  const ushort8v* row = (const ushort8v*)(scores + (size_t)n * DFF);
  unsigned short key[64];
#pragma unroll
  for (int i = 0; i < 8; i++) {
    ushort8v v = row[l * 8 + i];
#pragma unroll
    for (int e = 0; e < 8; e++) {
      unsigned short u = v[e];
      key[i * 8 + e] = (u & 0x8000u) ? (unsigned short)(~u)
                                     : (unsigned short)(u | 0x8000u);
    }
  }
  unsigned int prefix = 0;
#pragma unroll
  for (int bit = 15; bit >= 0; bit--) {
    unsigned int probe = prefix | (1u << bit);
    int c = 0;
#pragma unroll
    for (int i = 0; i < 64; i++) c += (key[i] >= probe) ? 1 : 0;
#pragma unroll
    for (int s = 1; s < 64; s <<= 1) c += __shfl_xor(c, s);
    if (c >= KCAND) prefix = probe;
  }
  unsigned short thr = (unsigned short)prefix;
  unsigned long long ltmask = (1ull << l) - 1ull;
  int base = 0;
  int* outp = cand + (size_t)n * KMAX;
#pragma unroll
  for (int i = 0; i < 64; i++) {
    bool p = key[i] >= thr;
    unsigned long long m = __ballot(p);
    if (p) {
      int pos = base + __popcll(m & ltmask);
      if (pos < KMAX) outp[pos] = l * 64 + i;
    }
    base += __popcll(m);
  }
  if (l == 0) cnt[n] = base < KMAX ? base : KMAX;
}

// ---------------- fp32 rescore of candidates -> exact top-32 set ----------------
__global__ __launch_bounds__(256) void rescore_kernel(const float* __restrict__ h,
    const float* __restrict__ w2f, const int* __restrict__ cand,
    const int* __restrict__ cnt, int* __restrict__ idx32) {
  __shared__ float sh[DM];
  __shared__ float sc[KMAX];
  __shared__ int sidx[KMAX];
  __shared__ int s_cnt;
  int n = blockIdx.x, tid = threadIdx.x;
  *(float4*)&sh[tid * 4] = *(const float4*)(h + (size_t)n * DM + tid * 4);
  if (tid == 0) s_cnt = cnt[n];
  if (tid < KMAX) { sidx[tid] = cand[(size_t)n * KMAX + tid]; sc[tid] = -INFINITY; }
  __syncthreads();
  int cntv = s_cnt;
  int w = tid >> 6, lane = tid & 63;
  for (int c = w; c < cntv; c += 4) {
    const float4* row = (const float4*)(w2f + (size_t)sidx[c] * DM);
    const float4* hp = (const float4*)sh;
    float s = 0.f;
#pragma unroll
    for (int t = 0; t < 4; t++) {
      float4 wv = row[t * 64 + lane];
      float4 hv = hp[t * 64 + lane];
      s = fmaf(wv.x, hv.x, s); s = fmaf(wv.y, hv.y, s);
      s = fmaf(wv.z, hv.z, s); s = fmaf(wv.w, hv.w, s);
    }
    for (int off = 32; off; off >>= 1) s += __shfl_xor(s, off);
    if (lane == 0) sc[c] = s;
  }
  __syncthreads();
  if (tid < cntv) {
    float st = sc[tid]; int it = sidx[tid];
    int rank = 0;
    for (int j = 0; j < KMAX; j++) {
      float sj = sc[j];
      rank += (sj > st) || (sj == st && sidx[j] < it);
    }
    if (rank < KSEL) idx32[(size_t)n * KSEL + rank] = it;
  }
}

// ------- per-neuron qkv table (bf16 out) -------
__global__ __launch_bounds__(384) void qkvtab_kernel(const float* __restrict__ nv,
    const float* __restrict__ ipw, const float* __restrict__ ipb,
    unsigned short* __restrict__ tab) {
  __shared__ float s_nv[8 * 128];
  int f0 = blockIdx.x * 8;
  int tid = threadIdx.x;
  for (int i = tid; i < 8 * 128; i += 384) s_nv[i] = nv[(size_t)f0 * 128 + i];
  __syncthreads();
  int row = tid;
  float bias = ipb[row];
  float acc[8];
#pragma unroll
  for (int ff = 0; ff < 8; ff++) acc[ff] = bias;
  const float* wr = ipw + (size_t)row * 128;
  for (int c = 0; c < 128; c++) {
    float w = wr[c];
#pragma unroll
    for (int ff = 0; ff < 8; ff++) acc[ff] = fmaf(s_nv[ff * 128 + c], w, acc[ff]);
  }
#pragma unroll
  for (int ff = 0; ff < 8; ff++) tab[(size_t)(f0 + ff) * 384 + row] = f2bf(acc[ff]);
}

// ---------------- tail v3: 1 token/block, 128 threads, k/v staged in LDS ----------------
#define AOS 132
__global__ __launch_bounds__(128) void tail3_kernel(
    const float* __restrict__ xf, const unsigned short* __restrict__ pats_b,
    const unsigned short* __restrict__ dirs_b, const unsigned short* __restrict__ qtab_b,
    const int* __restrict__ idxs,
    const unsigned short* __restrict__ opwb, const float* __restrict__ opb,
    const unsigned short* __restrict__ w1b, const float* __restrict__ b1,
    const float* __restrict__ w2, const float* __restrict__ b2,
    float* __restrict__ out) {
  __shared__ unsigned short s_kv[2 * 32 * 128];   // k rows then v rows; later aliased as s_at
  __shared__ unsigned short s_xf[1024];           // x row, bf16
  __shared__ unsigned short s_ao[32 * AOS];
  __shared__ float s_base[32];
  __shared__ float s_coef[32];
  __shared__ int s_idx[32];
  unsigned short* s_k = s_kv;
  unsigned short* s_v = s_kv + 32 * 128;
  unsigned short* s_at = s_kv;

  int n = blockIdx.x, tid = threadIdx.x;
  int w = tid >> 6, l = tid & 63;

  if (tid < 32) s_idx[tid] = idxs[(size_t)n * 32 + tid];
  {
    const float4* xr = (const float4*)(xf + (size_t)n * DM);
    float4 a = xr[tid * 2], b = xr[tid * 2 + 1];
    ushort8v o = {f2bf(a.x), f2bf(a.y), f2bf(a.z), f2bf(a.w),
                  f2bf(b.x), f2bf(b.y), f2bf(b.z), f2bf(b.w)};
    *(ushort8v*)&s_xf[tid * 8] = o;
  }
  __syncthreads();

#pragma unroll
  for (int p = 0; p < 8; p++) {
    int i = p * 128 + tid;
    int j = i >> 5, c = i & 31;
    int half = c >> 4, cc = c & 15;
    ushort8v v = *(const ushort8v*)(qtab_b + (size_t)s_idx[j] * 384 + 128 + half * 128 + cc * 8);
    *(ushort8v*)&s_kv[half * 4096 + j * 128 + cc * 8] = v;
  }

  {
    int j = tid >> 2, lq = tid & 3;
    const ushort8v* pr = (const ushort8v*)(pats_b + (size_t)s_idx[j] * 1024);
    float s = 0.f;
#pragma unroll 8
    for (int it = 0; it < 32; it++) {
      int g = it * 4 + lq;
      ushort8v pv = pr[g];
      const ushort8v xv = *(const ushort8v*)&s_xf[g * 8];
#pragma unroll
      for (int e = 0; e < 8; e++) s = fmaf(bf2f(pv[e]), bf2f(xv[e]), s);
    }
    s += __shfl_xor(s, 1);
    s += __shfl_xor(s, 2);
    if (lq == 0) s_base[j] = gelu_f(s);
  }
  __syncthreads();

  {
    int qj = l & 31;
#pragma unroll
    for (int p = 0; p < 2; p++) {
      int h0 = w * 4 + p * 2 + (l >> 5);
      const ushort8v* qr = (const ushort8v*)(qtab_b + (size_t)s_idx[qj] * 384 + h0 * 16);
      ushort8v q0 = qr[0], q1 = qr[1];
      float q[16];
#pragma unroll
      for (int e = 0; e < 8; e++) { q[e] = bf2f(q0[e]); q[8 + e] = bf2f(q1[e]); }
      float att[32];
#pragma unroll 8
      for (int kj = 0; kj < 32; kj++) {
        const ushort8v* kr = (const ushort8v*)&s_k[kj * 128 + h0 * 16];
        ushort8v k0 = kr[0], k1 = kr[1];
        float s = 0.f;
#pragma unroll
        for (int e = 0; e < 8; e++) s = fmaf(q[e], bf2f(k0[e]), s);
#pragma unroll
        for (int e = 0; e < 8; e++) s = fmaf(q[8 + e], bf2f(k1[e]), s);
        att[kj] = s * 0.25f;
      }
      float m = att[0];
#pragma unroll
      for (int k = 1; k < 32; k++) m = fmaxf(m, att[k]);
      float sum = 0.f;
#pragma unroll
      for (int k = 0; k < 32; k++) { att[k] = expf(att[k] - m); sum += att[k]; }
      float inv = 1.f / sum;
#pragma unroll
      for (int k = 0; k < 32; k++) att[k] *= inv;
      float o[16];
#pragma unroll
      for (int e = 0; e < 16; e++) o[e] = 0.f;
#pragma unroll 8
      for (int kj = 0; kj < 32; kj++) {
        const ushort8v* vr = (const ushort8v*)&s_v[kj * 128 + h0 * 16];
        ushort8v v0 = vr[0], v1 = vr[1];
        float a = att[kj];
#pragma unroll
        for (int e = 0; e < 8; e++) o[e] = fmaf(a, bf2f(v0[e]), o[e]);
#pragma unroll
        for (int e = 0; e < 8; e++) o[8 + e] = fmaf(a, bf2f(v1[e]), o[8 + e]);
      }
      ushort8v o0, o1;
#pragma unroll
      for (int e = 0; e < 8; e++) { o0[e] = f2bf(o[e]); o1[e] = f2bf(o[8 + e]); }
      ushort8v* ao = (ushort8v*)&s_ao[qj * AOS + h0 * 16];
      ao[0] = o0; ao[1] = o1;
    }
  }
  __syncthreads();

  {
    floatx4 acc[8];
#pragma unroll
    for (int nt = 0; nt < 8; nt++) acc[nt] = (floatx4){0.f, 0.f, 0.f, 0.f};
#pragma unroll
    for (int kst = 0; kst < 4; kst++) {
      short8 a = *(const short8*)&s_ao[(w * 16 + (l & 15)) * AOS + kst * 32 + (l >> 4) * 8];
#pragma unroll
      for (int nt = 0; nt < 8; nt++) {
        short8 b = *(const short8*)&opwb[(size_t)(nt * 16 + (l & 15)) * 128 + kst * 32 + (l >> 4) * 8];
        acc[nt] = __builtin_amdgcn_mfma_f32_16x16x32_bf16(a, b, acc[nt], 0, 0, 0);
      }
    }
#pragma unroll
    for (int nt = 0; nt < 8; nt++) {
      int col = nt * 16 + (l & 15);
      float bias = opb[col];
#pragma unroll
      for (int r = 0; r < 4; r++) {
        int row = w * 16 + (l >> 4) * 4 + r;
        s_at[row * AOS + col] = f2bf(acc[nt][r] + bias);
      }
    }
  }
  __syncthreads();

  {
    floatx4 acc[4];
#pragma unroll
    for (int nt = 0; nt < 4; nt++) acc[nt] = (floatx4){0.f, 0.f, 0.f, 0.f};
#pragma unroll
    for (int kst = 0; kst < 4; kst++) {
      short8 a = *(const short8*)&s_at[(w * 16 + (l & 15)) * AOS + kst * 32 + (l >> 4) * 8];
#pragma unroll
      for (int nt = 0; nt < 4; nt++) {
        short8 b = *(const short8*)&w1b[(size_t)(nt * 16 + (l & 15)) * 128 + kst * 32 + (l >> 4) * 8];
        acc[nt] = __builtin_amdgcn_mfma_f32_16x16x32_bf16(a, b, acc[nt], 0, 0, 0);
      }
    }
    float p[4] = {0.f, 0.f, 0.f, 0.f};
#pragma unroll
    for (int nt = 0; nt < 4; nt++) {
      int col = nt * 16 + (l & 15);
      float bb = b1[col], ww = w2[col];
#pragma unroll
      for (int r = 0; r < 4; r++)
        p[r] = fmaf(gelu_f(acc[nt][r] + bb), ww, p[r]);
    }
#pragma unroll
    for (int r = 0; r < 4; r++) {
      p[r] += __shfl_xor(p[r], 1);
      p[r] += __shfl_xor(p[r], 2);
      p[r] += __shfl_xor(p[r], 4);
      p[r] += __shfl_xor(p[r], 8);
    }
    if ((l & 15) == 0) {
      float b2v = b2[0];
#pragma unroll
      for (int r = 0; r < 4; r++) {
        int row = w * 16 + (l >> 4) * 4 + r;
        float sw = 1.f / (1.f + expf(-(p[r] + b2v)));
        s_coef[row] = s_base[row] * sw;
      }
    }
  }
  __syncthreads();

#pragma unroll
  for (int ii = 0; ii < 2; ii++) {
    int d0 = (ii * 128 + tid) * 4;
    float4 a = {0.f, 0.f, 0.f, 0.f};
#pragma unroll 8
    for (int j = 0; j < 32; j++) {
      float c = s_coef[j];
      ushort4v dv = *(const ushort4v*)&dirs_b[(size_t)s_idx[j] * 1024 + d0];
      a.x = fmaf(c, bf2f(dv.x), a.x);
      a.y = fmaf(c, bf2f(dv.y), a.y);
      a.z = fmaf(c, bf2f(dv.z), a.z);
      a.w = fmaf(c, bf2f(dv.w), a.w);
    }
    *(float4*)&out[(size_t)n * 1024 + d0] = a;
  }
}

extern "C" void kernel_launch(void* const* d_in, const int* in_sizes, int n_in,
                              void* d_out, int out_size, void* d_ws, size_t ws_size,
                              hipStream_t stream) {
  const float* x    = (const float*)d_in[0];
  const float* pats = (const float*)d_in[1];
  const float* nv   = (const float*)d_in[2];
  const float* dirs = (const float*)d_in[3];
  const float* rw1  = (const float*)d_in[4];
  const float* rw2  = (const float*)d_in[5];
  const float* lng  = (const float*)d_in[6];
  const float* lnb  = (const float*)d_in[7];
  const float* ipw  = (const float*)d_in[8];
  const float* ipb  = (const float*)d_in[9];
  const float* opw  = (const float*)d_in[10];
  const float* opb  = (const float*)d_in[11];
  const float* w1   = (const float*)d_in[12];
  const float* b1   = (const float*)d_in[13];
  const float* w2   = (const float*)d_in[14];
  const float* b2   = (const float*)d_in[15];
  float* out = (float*)d_out;

  const size_t MB = 1u << 20;
  char* ws = (char*)d_ws;
  float* xn            = (float*)(ws + 0);                 // 16 MB
  float* h             = (float*)(ws + 16 * MB);           // 16 MB
  unsigned short* sb   = (unsigned short*)(ws + 32 * MB);  // 32 MB (bf16 scores)
  unsigned short* qtab = (unsigned short*)(ws + 64 * MB);  // 3 MB
  unsigned short* hb   = (unsigned short*)(ws + 67 * MB);  // 8 MB
  unsigned short* w2b  = (unsigned short*)(ws + 75 * MB);  // 8 MB
  unsigned short* patsb= (unsigned short*)(ws + 83 * MB);  // 8 MB
  unsigned short* dirsb= (unsigned short*)(ws + 91 * MB);  // 8 MB
  unsigned short* opwb = (unsigned short*)(ws + 99 * MB);  // 32 KB
  unsigned short* w1b  = (unsigned short*)(ws + 99 * MB + 64 * 1024);  // 16 KB
  int* idx32           = (int*)(ws + 100 * MB);            // 512 KB
  int* cand            = (int*)(ws + 101 * MB);            // 1 MB
  int* cnt             = (int*)(ws + 102 * MB);            // 16 KB

  ln_kernel<<<N_TOK, 256, 0, stream>>>(x, lng, lnb, xn);
  gemm1_kernel<<<dim3(DM / 32, N_TOK / 256), 256, 0, stream>>>(xn, rw1, h, hb);
  cvt_bf16<<<(DFF * DM) / 1024, 256, 0, stream>>>(rw2, w2b);
  cvt_bf16<<<(DFF * DM) / 1024, 256, 0, stream>>>(pats, patsb);
  cvt_bf16<<<(DFF * DM) / 1024, 256, 0, stream>>>(dirs, dirsb);
  cvt_bf16<<<(DN * DN) / 1024, 256, 0, stream>>>(opw, opwb);
  cvt_bf16<<<(DN * DN / 2) / 1024, 256, 0, stream>>>(w1, w1b);
  gemm_bf<<<dim3(DFF / 128, N_TOK / 128), 256, 0, stream>>>(hb, w2b, sb);
  topk2_kernel<<<N_TOK / 4, 256, 0, stream>>>(sb, cand, cnt);
  rescore_kernel<<<N_TOK, 256, 0, stream>>>(h, rw2, cand, cnt, idx32);
  qkvtab_kernel<<<DFF / 8, 384, 0, stream>>>(nv, ipw, ipb, qtab);
  tail3_kernel<<<N_TOK, 128, 0, stream>>>(x, patsb, dirsb, qtab, idx32,
                                          opwb, opb, w1b, b1, w2, b2, out);
}